// Round 9
// baseline (3770.058 us; speedup 1.0000x reference)
//
#include <hip/hip_runtime.h>
#include <hip/hip_bf16.h>
#include <hip/hip_fp16.h>

// EncoderRNN: emb gather -> biLSTM(L0) -> biLSTM(L1) -> last-step output.
//   1) embed gather -> X0 bf16 [T*B, 256]
//   2) GEMM P0: G = X0 @ W0^T + b (fwd|bwd packed, N=2048), G fp16 [T*B,2048]
//   3) scan S0: per (dir, 32-batch dslice) recurrence split across 4 WGs
//      (hidden-quarter each, weights LDS-resident). h exchange: SENTINEL
//      protocol — hexch pre-filled 0xFF; writers publish h via per-wave
//      RELEASE atomic b64 stores; readers ACQUIRE-poll the data words
//      directly (no flags, no barriers in the steady-state loop).
//   4) GEMM P1: fwd cols (N=1024) + tiny t=127 bwd GEMM
//   5) scan S1 (fwd only), h exchanged through dead X0 region -> out[:, :256]
//   6) bwd1 elementwise (t=127, h0=c0=0) -> out[:, 256:512]

typedef short s8v __attribute__((ext_vector_type(8)));
typedef float f4v __attribute__((ext_vector_type(4)));
typedef unsigned short u16v8 __attribute__((ext_vector_type(8)));

#define SENT 0xFFFFFFFFFFFFFFFFULL   // 4x bf16 0xFFFF (-NaN): unreachable by f2bf(finite)

__device__ inline unsigned short f2bf(float x) {
  union { float f; unsigned u; } v; v.f = x;
  unsigned r = v.u + 0x7fffu + ((v.u >> 16) & 1u);
  return (unsigned short)(r >> 16);
}

__device__ inline void gload_lds16(const void* g, void* l) {
  __builtin_amdgcn_global_load_lds((const __attribute__((address_space(1))) unsigned int*)g,
                                   (__attribute__((address_space(3))) unsigned int*)l,
                                   16, 0, 0);
}

__device__ inline float sigm(float x) { return 1.f / (1.f + __expf(-x)); }
__device__ inline float tanh_f(float x) {
  float e = __expf(2.f * x);
  return 1.f - 2.f / (e + 1.f);
}

// ---------------- embedding gather + bf16 cast -------------------------------
__global__ __launch_bounds__(256) void embed_kernel(
    const int* __restrict__ idc, const float* __restrict__ emb,
    unsigned short* __restrict__ x0)
{
  int e = (blockIdx.x * 256 + threadIdx.x) * 8;   // into [32768*256]
  int m = e >> 8;
  int col = e & 255;
  int t = m >> 8, b = m & 255;
  int idx = idc[b * 128 + t];
  const float* src = emb + (size_t)idx * 256 + col;
  float4 lo = *(const float4*)src;
  float4 hi = *(const float4*)(src + 4);
  u16v8 o;
  o[0]=f2bf(lo.x); o[1]=f2bf(lo.y); o[2]=f2bf(lo.z); o[3]=f2bf(lo.w);
  o[4]=f2bf(hi.x); o[5]=f2bf(hi.y); o[6]=f2bf(hi.z); o[7]=f2bf(hi.w);
  *(u16v8*)(x0 + e) = o;
}

// ---------------- weight packing --------------------------------------------
__global__ __launch_bounds__(256) void pack2_bf16(unsigned short* __restrict__ dst,
    const float* __restrict__ s0, const float* __restrict__ s1, int n_each)
{
  int i = (blockIdx.x * 256 + threadIdx.x) * 4;
  const float* s = (i < n_each) ? (s0 + i) : (s1 + (i - n_each));
  float4 v = *(const float4*)s;
  dst[i] = f2bf(v.x); dst[i+1] = f2bf(v.y); dst[i+2] = f2bf(v.z); dst[i+3] = f2bf(v.w);
}

__global__ __launch_bounds__(256) void pack2_f32(float* __restrict__ dst,
    const float* __restrict__ s0, const float* __restrict__ s1, int n_each)
{
  int i = blockIdx.x * 256 + threadIdx.x;
  dst[i] = (i < n_each) ? s0[i] : s1[i - n_each];
}

// w_hh [1024,256] fp32 -> bf16 MFMA-B-fragment stream:
// dst[((nt*8+ks)*64 + l)*8 + j] = w[(nt*16 + (l&15))*256 + ks*32 + (l>>4)*8 + j]
__global__ __launch_bounds__(256) void pack_whh(short* __restrict__ dst,
                                                const float* __restrict__ w)
{
  int tid = blockIdx.x * 256 + threadIdx.x;   // 0..32767
  int nt = tid >> 9, ks = (tid >> 6) & 7, l = tid & 63;
  const float* src = w + (size_t)(nt*16 + (l & 15))*256 + ks*32 + (l >> 4)*8;
  float4 a = *(const float4*)src;
  float4 b = *(const float4*)(src + 4);
  s8v o;
  o[0]=(short)f2bf(a.x); o[1]=(short)f2bf(a.y); o[2]=(short)f2bf(a.z); o[3]=(short)f2bf(a.w);
  o[4]=(short)f2bf(b.x); o[5]=(short)f2bf(b.y); o[6]=(short)f2bf(b.z); o[7]=(short)f2bf(b.w);
  *(s8v*)(dst + (size_t)tid*8) = o;
}

// ---------------- input-projection GEMM: G = A @ W^T + bias (fp16 out) ------
__global__ __launch_bounds__(256, 2) void gemm_bt(
    const unsigned short* __restrict__ A, const unsigned short* __restrict__ W,
    const float* __restrict__ bias, _Float16* __restrict__ Gout, int K)
{
  __shared__ char lds[65536];     // 2 x (A 16K + B 16K)
  const int tid = threadIdx.x, l = tid & 63, w = tid >> 6;
  const int m0 = blockIdx.x * 128, n0 = blockIdx.y * 128;
  const int wr = w >> 1, wc = w & 1;
  const int NK = K >> 6;
  const int c15 = l & 15, ld4 = l >> 4;

  f4v acc[4][4];
  #pragma unroll
  for (int i = 0; i < 4; ++i)
    #pragma unroll
    for (int j = 0; j < 4; ++j) acc[i][j] = (f4v){0.f,0.f,0.f,0.f};

  auto stage = [&](int kt, int buf) {
    char* base = lds + buf*32768;
    const unsigned short* As = A + (size_t)m0*K + kt*64;
    const unsigned short* Ws = W + (size_t)n0*K + kt*64;
    int rr8 = l >> 3;
    int sl = (l & 7) ^ rr8;          // pre-swizzled source slot
    #pragma unroll
    for (int j = 0; j < 4; ++j) {
      int rb = (w*4 + j)*8;
      gload_lds16(As + (size_t)(rb + rr8)*K + sl*8, base + (w*4+j)*1024);
      gload_lds16(Ws + (size_t)(rb + rr8)*K + sl*8, base + 16384 + (w*4+j)*1024);
    }
  };

  stage(0, 0);
  __syncthreads();
  for (int kt = 0; kt < NK; ++kt) {
    const int cur = kt & 1;
    if (kt + 1 < NK) stage(kt+1, cur^1);
    const char* ab = lds + cur*32768;
    const char* bb = ab + 16384;
    #pragma unroll
    for (int ks = 0; ks < 2; ++ks) {
      s8v af[4], bf[4];
      #pragma unroll
      for (int mt = 0; mt < 4; ++mt) {
        int row = wr*64 + mt*16 + c15;
        int cb = ks*64 + ld4*16;
        af[mt] = *(const s8v*)(ab + row*128 + (cb ^ ((row & 7) << 4)));
      }
      #pragma unroll
      for (int nt = 0; nt < 4; ++nt) {
        int row = wc*64 + nt*16 + c15;
        int cb = ks*64 + ld4*16;
        bf[nt] = *(const s8v*)(bb + row*128 + (cb ^ ((row & 7) << 4)));
      }
      #pragma unroll
      for (int mt = 0; mt < 4; ++mt)
        #pragma unroll
        for (int nt = 0; nt < 4; ++nt)
          acc[mt][nt] = __builtin_amdgcn_mfma_f32_16x16x32_bf16(af[mt], bf[nt], acc[mt][nt], 0, 0, 0);
    }
    __syncthreads();
  }
  #pragma unroll
  for (int nt = 0; nt < 4; ++nt) {
    int n = n0 + wc*64 + nt*16 + c15;
    float bv = bias[n];
    #pragma unroll
    for (int mt = 0; mt < 4; ++mt) {
      int mb = m0 + wr*64 + mt*16 + ld4*4;
      #pragma unroll
      for (int j = 0; j < 4; ++j)
        Gout[(size_t)(mb + j)*2048 + n] = (_Float16)(acc[mt][nt][j] + bv);
    }
  }
}

// ---------------- split-recurrence LSTM scan (sentinel protocol) -------------
// Group = (dir, 32-row dslice); 4 WGs per group, WG = hidden-quarter q.
// 8 waves; wave w -> slice s=w>>2 (16 rows), subtile u=w&3 (16 hd), 4 gates.
// Weights (128 KB) LDS-resident. hexch pre-filled 0xFF (sentinel). Writer:
// per-wave RELEASE atomic b64 store of its h subtile. Reader: per-lane
// ACQUIRE-poll of its 16 A-fragment words until all != sentinel (polled data
// feeds MFMA directly). No flags; no barriers in the steady-state loop.
__global__ __launch_bounds__(512, 1) void scan_kernel(
    const _Float16* __restrict__ G,     // [T,256,2048] (+dir*1024 col offset)
    const short* __restrict__ whhF, const short* __restrict__ whhB,
    unsigned short* __restrict__ hexch, int hstride,
    float* __restrict__ fout,           // out cols 0:256 (scan1) or null
    int T)
{
  __shared__ char lds[151552];      // 128K weights + 16K G-strips + 4K htb
  char* wlds = lds;
  char* gstr = lds + 131072;        // [s][u][j 2][1024]  per-wave strips
  char* htb  = lds + 147456;        // [wave 8][row 16][col 16] bf16 bounce

  const int tid = threadIdx.x;
  const int l = tid & 63;
  const int w = tid >> 6;           // 0..7
  const int ds = blockIdx.x;        // dslice 0..7
  const int dir = blockIdx.y;
  const int q = blockIdx.z;         // hidden quarter 0..3
  const int b0 = ds * 32;
  const int hcol = dir * 256;
  const short* __restrict__ whh = dir ? whhB : whhF;
  const int ld4 = l >> 4;
  const int c15 = l & 15;
  const int s = w >> 2;             // slice within WG
  const int u = w & 3;              // 16-hd subtile within quarter

  // weights -> LDS: idx2 = (g*4+u)*8+ks ; nt = g*16 + q*4 + u
  #pragma unroll
  for (int j = 0; j < 16; ++j) {
    int idx2 = w*16 + j;
    int g = idx2 >> 5, rem = idx2 & 31, uu = rem >> 3, ks = rem & 7;
    int nt = g*16 + q*4 + uu;
    gload_lds16(whh + ((size_t)(nt*8 + ks)*64 + l)*8, wlds + idx2*1024);
  }

  char* gbase = gstr + (s*4 + u)*2048;

  float cst[4];
  #pragma unroll
  for (int i = 0; i < 4; ++i) cst[i] = 0.f;

  for (int t = 0; t < T; ++t) {
    const int teff = dir ? (T - 1 - t) : t;

    // stage this step's G strips (per-wave: exactly the gate-cols we consume)
    // instruction j covers gates 2j,2j+1: lane l -> gate 2j+(l&1), row l>>2,
    // 16B-half (l>>1)&1 of the 32B strip.
    #pragma unroll
    for (int j = 0; j < 2; ++j) {
      int g = j*2 + (l & 1);
      const char* src = (const char*)G +
          ((size_t)(teff*256 + b0 + s*16 + (l >> 2)))*4096 +
          dir*2048 + g*512 + q*128 + u*32 + ((l >> 1) & 1)*16;
      gload_lds16(src, gbase + j*1024);
    }
    if (t == 0) __syncthreads();    // drain weights + t0 G-strips (cross-wave wlds)

    f4v acc[4];
    #pragma unroll
    for (int i = 0; i < 4; ++i) acc[i] = (f4v){0.f,0.f,0.f,0.f};

    if (t > 0) {
      const int tprev = dir ? (T - t) : (t - 1);
      const unsigned long long* hq = (const unsigned long long*)(hexch +
          ((size_t)tprev*256 + b0 + s*16 + c15)*hstride + hcol + ld4*8);
      unsigned long long wd[16];
      // acquire-poll own 16 words (ks*8 + part) until none is the sentinel.
      // per-iteration acquire (inv) keeps retries coherent even if the
      // relaxed loads behave like plain loads. vmcnt(0) inside the acquire
      // also drains our G-strip gload_lds for free.
      for (;;) {
        wd[0] = __hip_atomic_load(hq, __ATOMIC_ACQUIRE, __HIP_MEMORY_SCOPE_AGENT);
        int ok = (wd[0] != SENT);
        #pragma unroll
        for (int i = 1; i < 16; ++i) {
          wd[i] = __hip_atomic_load(hq + (i >> 1)*8 + (i & 1),
                                    __ATOMIC_RELAXED, __HIP_MEMORY_SCOPE_AGENT);
          ok &= (wd[i] != SENT);
        }
        if (__all(ok)) break;
      }
      s8v a[8];
      #pragma unroll
      for (int ks = 0; ks < 8; ++ks) {
        union { unsigned long long u2[2]; s8v v; } cv;
        cv.u2[0] = wd[ks*2]; cv.u2[1] = wd[ks*2 + 1];
        a[ks] = cv.v;
      }
      #pragma unroll
      for (int g = 0; g < 4; ++g)
        #pragma unroll
        for (int ks = 0; ks < 8; ++ks) {
          s8v b = *(const s8v*)(wlds + ((size_t)((g*4 + u)*8 + ks))*1024 + l*16);
          acc[g] = __builtin_amdgcn_mfma_f32_16x16x32_bf16(a[ks], b, acc[g], 0, 0, 0);
        }
    } else {
      // t==0: no h term; G-strips drained by the syncthreads above
    }

    // epilogue: gates -> c,h ; h -> per-wave LDS tile (same-wave ordering)
    const bool last = (t == T - 1);
    #pragma unroll
    for (int r = 0; r < 4; ++r) {
      const int row = ld4*4 + r;
      // G strip read-back: gate g at lane l' = (row<<2)|((c15>>3)<<1)|(g&1)
      auto gld = [&](int g) -> float {
        int lp = (row << 2) | (((c15 >> 3) & 1) << 1) | (g & 1);
        return (float)*(const _Float16*)(gbase + (g >> 1)*1024 + lp*16 + (c15 & 7)*2);
      };
      float pi = acc[0][r] + gld(0);
      float pf = acc[1][r] + gld(1);
      float pg = acc[2][r] + gld(2);
      float po = acc[3][r] + gld(3);
      float cn = sigm(pf) * cst[r] + sigm(pi) * tanh_f(pg);
      cst[r] = cn;
      float hv = sigm(po) * tanh_f(cn);
      *(unsigned short*)(htb + w*512 + row*32 + c15*2) = f2bf(hv);
      if (fout && last) fout[(b0 + s*16 + row)*512 + q*64 + u*16 + c15] = hv;
    }
    // publish: lane l -> row l>>2, 4-col chunk l&3; single per-wave RELEASE
    // atomic b64 store (waitcnt + wbl2(nearly empty) + sc-store to LLC).
    {
      unsigned long long hval = *(const unsigned long long*)
          (htb + w*512 + (l >> 2)*32 + (l & 3)*8);
      unsigned long long* dst = (unsigned long long*)(hexch +
          ((size_t)teff*256 + b0 + s*16 + (l >> 2))*hstride + hcol +
          q*64 + u*16 + (l & 3)*4);
      __hip_atomic_store(dst, hval, __ATOMIC_RELEASE, __HIP_MEMORY_SCOPE_AGENT);
    }
    // no barrier: waves free-run; all cross-wave deps go through hexch polls
  }
}

// ---------------- layer-1 backward: only its first step reaches the output --
__global__ __launch_bounds__(256) void bwd1_kernel(const _Float16* __restrict__ G,
                                                   float* __restrict__ out)
{
  int tid = blockIdx.x * 256 + threadIdx.x;   // 65536 = 256 b x 256 hd
  int b = tid >> 8, hd = tid & 255;
  const _Float16* g = G + ((size_t)(127*256 + b))*2048 + 1024;
  float pi = (float)g[hd];
  float pg = (float)g[512 + hd];
  float po = (float)g[768 + hd];
  float cn = sigm(pi) * tanh_f(pg);
  out[b*512 + 256 + hd] = sigm(po) * tanh_f(cn);
}

// ---------------- launch -----------------------------------------------------
extern "C" void kernel_launch(void* const* d_in, const int* in_sizes, int n_in,
                              void* d_out, int out_size, void* d_ws, size_t ws_size,
                              hipStream_t stream)
{
  (void)in_sizes; (void)n_in; (void)out_size; (void)ws_size;
  const int*   idc   = (const int*)d_in[0];
  const float* emb   = (const float*)d_in[1];
  const float* wih0f = (const float*)d_in[2];
  const float* whh0f = (const float*)d_in[3];
  const float* b0f   = (const float*)d_in[4];
  const float* wih0b = (const float*)d_in[5];
  const float* whh0b = (const float*)d_in[6];
  const float* b0b   = (const float*)d_in[7];
  const float* wih1f = (const float*)d_in[8];
  const float* whh1f = (const float*)d_in[9];
  const float* b1f   = (const float*)d_in[10];
  const float* wih1b = (const float*)d_in[11];
  const float* b1b   = (const float*)d_in[13];

  char* ws = (char*)d_ws;                                   // ~189.3 MB used
  unsigned short* X0   = (unsigned short*)(ws);             // 16,777,216 B (embeds; later scan1 hexch [128][256][256])
  unsigned short* Y0   = (unsigned short*)(ws + 16777216);  // 33,554,432 B (scan0 hexch == layer-1 input)
  _Float16*       Gb   = (_Float16*)(ws + 50331648);        // 134,217,728 B
  unsigned short* W0P  = (unsigned short*)(ws + 184549376); // 1,048,576 B
  unsigned short* W1P  = (unsigned short*)(ws + 185597952); // 2,097,152 B
  short*          WH0F = (short*)(ws + 187695104);          // 524,288 B
  short*          WH0B = (short*)(ws + 188219392);          // 524,288 B
  short*          WH1F = (short*)(ws + 188743680);          // 524,288 B
  float*          B0P  = (float*)(ws + 189267968);          // 8,192 B
  float*          B1P  = (float*)(ws + 189276160);          // 8,192 B
  float* out = (float*)d_out;

  // sentinel pre-fill of scan0's exchange buffer (Y0)
  hipMemsetAsync(Y0, 0xFF, 33554432, stream);

  embed_kernel<<<dim3(4096), dim3(256), 0, stream>>>(idc, emb, X0);
  pack2_bf16<<<dim3(512),  dim3(256), 0, stream>>>(W0P, wih0f, wih0b, 262144);
  pack2_bf16<<<dim3(1024), dim3(256), 0, stream>>>(W1P, wih1f, wih1b, 524288);
  pack2_f32 <<<dim3(8),    dim3(256), 0, stream>>>(B0P, b0f, b0b, 1024);
  pack2_f32 <<<dim3(8),    dim3(256), 0, stream>>>(B1P, b1f, b1b, 1024);
  pack_whh  <<<dim3(128),  dim3(256), 0, stream>>>(WH0F, whh0f);
  pack_whh  <<<dim3(128),  dim3(256), 0, stream>>>(WH0B, whh0b);
  pack_whh  <<<dim3(128),  dim3(256), 0, stream>>>(WH1F, whh1f);

  // L0: full gate GEMM (both dirs) + split bi-directional scan (h via Y0)
  gemm_bt<<<dim3(256, 16), dim3(256), 0, stream>>>(X0, W0P, B0P, Gb, 256);
  scan_kernel<<<dim3(8, 2, 4), dim3(512), 0, stream>>>(
      Gb, WH0F, WH0B, Y0, 512, (float*)nullptr, 128);

  // sentinel pre-fill of scan1's exchange buffer (dead X0 region, 16 MB)
  hipMemsetAsync(X0, 0xFF, 16777216, stream);

  // L1: fwd gates for all t (N=1024) + bwd gates only for t=127
  gemm_bt<<<dim3(256, 8), dim3(256), 0, stream>>>(Y0, W1P, B1P, Gb, 512);
  gemm_bt<<<dim3(2, 8), dim3(256), 0, stream>>>(
      Y0 + (size_t)127*256*512, W1P + (size_t)1024*512, B1P + 1024,
      Gb + (size_t)127*256*2048 + 1024, 512);

  // L1 fwd scan (h via X0 region, stride 256)
  scan_kernel<<<dim3(8, 1, 4), dim3(512), 0, stream>>>(
      Gb, WH1F, WH1F, X0, 256, out, 128);
  bwd1_kernel<<<dim3(256), dim3(256), 0, stream>>>(Gb, out);
}